// Round 1
// baseline (148.824 us; speedup 1.0000x reference)
//
#include <hip/hip_runtime.h>
#include <stdint.h>

#define HEADS 12
#define DMODEL 768
#define BATCH 2
#define SEQ 2048
#define BS (BATCH * SEQ)
#define HD 64

typedef float f32x4 __attribute__((ext_vector_type(4)));
typedef __bf16 bf16x8 __attribute__((ext_vector_type(8)));
typedef unsigned short u16;
typedef u16 u16x8 __attribute__((ext_vector_type(8)));

__device__ __forceinline__ u16 f2b(float f) {
    return __builtin_bit_cast(u16, (__bf16)f);
}

__device__ __forceinline__ void gld_lds16(const void* g, void* l) {
    __builtin_amdgcn_global_load_lds(
        (__attribute__((address_space(1))) void*)(g),
        (__attribute__((address_space(3))) void*)(l), 16, 0, 0);
}

// ---------------- prep: fp32 -> bf16 (vectorized) ----------------
__global__ __launch_bounds__(256) void cvt_x(
    const float* __restrict__ q, const float* __restrict__ k, const float* __restrict__ v,
    u16* __restrict__ xq, u16* __restrict__ xk, u16* __restrict__ xv) {
    int z = blockIdx.z;
    const float* s = (z == 0) ? q : (z == 1) ? k : v;
    u16* d = (z == 0) ? xq : (z == 1) ? xk : xv;
    size_t i = (size_t)blockIdx.x * blockDim.x + threadIdx.x;
    const float4* s4 = (const float4*)s;
    float4 a = s4[2 * i], b = s4[2 * i + 1];
    u16x8 o;
    o[0] = f2b(a.x); o[1] = f2b(a.y); o[2] = f2b(a.z); o[3] = f2b(a.w);
    o[4] = f2b(b.x); o[5] = f2b(b.y); o[6] = f2b(b.z); o[7] = f2b(b.w);
    *(u16x8*)(d + 8 * i) = o;
}

// ---------------- prep: W -> W^T bf16 ----------------
__global__ void cvt_wt(const float* __restrict__ wq, const float* __restrict__ wk,
                       const float* __restrict__ wv,
                       u16* __restrict__ tq, u16* __restrict__ tk, u16* __restrict__ tv) {
    int z = blockIdx.z;
    const float* w = (z == 0) ? wq : (z == 1) ? wk : wv;
    u16* t = (z == 0) ? tq : (z == 1) ? tk : tv;
    __shared__ float tile[32][33];
    int tx = threadIdx.x, ty = threadIdx.y;
    int kb = blockIdx.y * 32, nb = blockIdx.x * 32;
    for (int r = 0; r < 32; r += 8)
        tile[ty + r][tx] = w[(size_t)(kb + ty + r) * DMODEL + nb + tx];
    __syncthreads();
    for (int r = 0; r < 32; r += 8)
        t[(size_t)(nb + ty + r) * DMODEL + kb + tx] = f2b(tile[tx][ty + r]);
}

// ---------------- projection GEMM: C[m][n] = X[m][k] * W[k][n] ----------------
// X: [BS][768] bf16, WT: [768 n][768 k] bf16.
// z=0/1 -> out [B,H,S,64]; z=2 -> out [B,H,64,S] (V stored transposed for attention)
__global__ __launch_bounds__(256, 2) void proj_gemm(
    const u16* __restrict__ xq, const u16* __restrict__ xk, const u16* __restrict__ xv,
    const u16* __restrict__ tq, const u16* __restrict__ tk, const u16* __restrict__ tv,
    u16* __restrict__ oq, u16* __restrict__ ok, u16* __restrict__ ov) {
    const int z = blockIdx.z;
    const u16* X  = (z == 0) ? xq : (z == 1) ? xk : xv;
    const u16* WT = (z == 0) ? tq : (z == 1) ? tk : tv;
    u16* Out      = (z == 0) ? oq : (z == 1) ? ok : ov;

    __shared__ u16 As[128 * 64];  // [row][64k], 128B rows, XOR-swizzled
    __shared__ u16 Bs[128 * 64];  // WT rows (n), same layout

    const int tid = threadIdx.x;
    const int lane = tid & 63, w = tid >> 6;
    const int wm = w >> 1, wn = w & 1;
    const int m0 = blockIdx.x * 128, n0 = blockIdx.y * 128;

    f32x4 acc[4][4] = {};

    for (int kt = 0; kt < DMODEL / 64; ++kt) {
        // stage A and WT tiles: linear LDS dest, inverse-swizzled global source
#pragma unroll
        for (int p = 0; p < 4; ++p) {
            int o = (p * 4 + w) * 1024 + lane * 16;
            int row = o >> 7;
            int col = (o & 127) ^ ((row & 7) << 4);
            gld_lds16((const char*)X + (size_t)(m0 + row) * (DMODEL * 2) + kt * 128 + col,
                      (char*)As + (p * 4 + w) * 1024);
            gld_lds16((const char*)WT + (size_t)(n0 + row) * (DMODEL * 2) + kt * 128 + col,
                      (char*)Bs + (p * 4 + w) * 1024);
        }
        __syncthreads();
#pragma unroll
        for (int kk = 0; kk < 2; ++kk) {
            bf16x8 af[4], bfr[4];
#pragma unroll
            for (int mi = 0; mi < 4; ++mi) {
                int row = wm * 64 + mi * 16 + (lane & 15);
                int col = (kk * 64 + ((lane >> 4) << 4)) ^ ((row & 7) << 4);
                af[mi] = *(const bf16x8*)((const char*)As + row * 128 + col);
            }
#pragma unroll
            for (int ni = 0; ni < 4; ++ni) {
                int row = wn * 64 + ni * 16 + (lane & 15);
                int col = (kk * 64 + ((lane >> 4) << 4)) ^ ((row & 7) << 4);
                bfr[ni] = *(const bf16x8*)((const char*)Bs + row * 128 + col);
            }
#pragma unroll
            for (int mi = 0; mi < 4; ++mi)
#pragma unroll
                for (int ni = 0; ni < 4; ++ni)
                    acc[mi][ni] = __builtin_amdgcn_mfma_f32_16x16x32_bf16(
                        af[mi], bfr[ni], acc[mi][ni], 0, 0, 0);
        }
        __syncthreads();
    }

    // epilogue: C/D layout col=lane&15, row=(lane>>4)*4+r (m89-verified)
#pragma unroll
    for (int mi = 0; mi < 4; ++mi) {
        int mb = m0 + wm * 64 + mi * 16 + ((lane >> 4) << 2);
#pragma unroll
        for (int ni = 0; ni < 4; ++ni) {
            int n = n0 + wn * 64 + ni * 16 + (lane & 15);
            int h = n >> 6, dd = n & 63;
#pragma unroll
            for (int r = 0; r < 4; ++r) {
                int m = mb + r;
                int b = m >> 11, s = m & 2047;
                u16 val = f2b(acc[mi][ni][r]);
                size_t off = (z == 2)
                    ? ((size_t)(b * HEADS + h) * HD + dd) * SEQ + s
                    : ((size_t)(b * HEADS + h) * SEQ + s) * HD + dd;
                Out[off] = val;
            }
        }
    }
}

// ---------------- fused attention ----------------
// qw,kw: [B,H,S,64] bf16; vt: [B,H,64,S] bf16
__global__ __launch_bounds__(256, 2) void attn(
    const u16* __restrict__ qw, const u16* __restrict__ kw, const u16* __restrict__ vt,
    const float* __restrict__ v_mask, const float* __restrict__ q_mask,
    float* __restrict__ out) {
    __shared__ u16 Ks[64 * 64];      // [k][d] swizzled
    __shared__ u16 Vs[64 * 64];      // [d][k] swizzled (V^T)
    __shared__ u16 Ps[4][32 * 64];   // per-wave P, swizzled
    __shared__ float bias[64];

    const int tid = threadIdx.x;
    const int lane = tid & 63, w = tid >> 6;
    const int bh = blockIdx.y;
    const int b = bh / HEADS, h = bh % HEADS;
    const int q0 = blockIdx.x * 128 + w * 32;

    const u16* qb = qw + (size_t)bh * SEQ * HD;
    const u16* kb = kw + (size_t)bh * SEQ * HD;
    const u16* vb = vt + (size_t)bh * HD * SEQ;

    // hoist Q fragments: A-layout row=lane&15, k = 8*(lane>>4)+j (+32*ks)
    bf16x8 qf[2][2];
#pragma unroll
    for (int qt = 0; qt < 2; ++qt)
#pragma unroll
        for (int ks = 0; ks < 2; ++ks) {
            int row = q0 + qt * 16 + (lane & 15);
            int cb = ks * 64 + ((lane >> 4) << 4);
            qf[qt][ks] = *(const bf16x8*)((const char*)(qb + (size_t)row * HD) + cb);
        }

    f32x4 accO[2][4] = {};
    float mrow[2][4], lrow[2][4];
#pragma unroll
    for (int qt = 0; qt < 2; ++qt)
#pragma unroll
        for (int r = 0; r < 4; ++r) { mrow[qt][r] = -1e30f; lrow[qt][r] = 0.f; }

    for (int t = 0; t < SEQ / 64; ++t) {
        const int kv0 = t * 64;
#pragma unroll
        for (int p = 0; p < 2; ++p) {
            int o = (p * 4 + w) * 1024 + lane * 16;
            int row = o >> 7;
            int col = (o & 127) ^ ((row & 7) << 4);
            gld_lds16((const char*)(kb + (size_t)(kv0 + row) * HD) + col,
                      (char*)Ks + (p * 4 + w) * 1024);
            gld_lds16((const char*)(vb + (size_t)row * SEQ + kv0) + col,
                      (char*)Vs + (p * 4 + w) * 1024);
        }
        if (tid < 64) bias[tid] = (1.0f - v_mask[b * SEQ + kv0 + tid]) * -1e10f;
        __syncthreads();

        // S = Q K^T  (16 MFMA)
        f32x4 sc[2][4] = {};
#pragma unroll
        for (int kk = 0; kk < 2; ++kk) {
            bf16x8 kf[4];
#pragma unroll
            for (int kt2 = 0; kt2 < 4; ++kt2) {
                int row = kt2 * 16 + (lane & 15);
                int col = (kk * 64 + ((lane >> 4) << 4)) ^ ((row & 7) << 4);
                kf[kt2] = *(const bf16x8*)((const char*)Ks + row * 128 + col);
            }
#pragma unroll
            for (int qt = 0; qt < 2; ++qt)
#pragma unroll
                for (int kt2 = 0; kt2 < 4; ++kt2)
                    sc[qt][kt2] = __builtin_amdgcn_mfma_f32_16x16x32_bf16(
                        qf[qt][kk], kf[kt2], sc[qt][kt2], 0, 0, 0);
        }

        float bia[4];
#pragma unroll
        for (int kt2 = 0; kt2 < 4; ++kt2) bia[kt2] = bias[kt2 * 16 + (lane & 15)];

        // online softmax (rows live in C-layout: row=(lane>>4)*4+r, col=lane&15)
#pragma unroll
        for (int qt = 0; qt < 2; ++qt) {
            float alpha[4];
#pragma unroll
            for (int r = 0; r < 4; ++r) {
                float rm = -1e30f;
#pragma unroll
                for (int kt2 = 0; kt2 < 4; ++kt2) {
                    float vsc = sc[qt][kt2][r] * 0.125f + bia[kt2];
                    sc[qt][kt2][r] = vsc;
                    rm = fmaxf(rm, vsc);
                }
                for (int msk = 1; msk < 16; msk <<= 1)
                    rm = fmaxf(rm, __shfl_xor(rm, msk));
                float mnew = fmaxf(mrow[qt][r], rm);
                alpha[r] = __expf(mrow[qt][r] - mnew);
                mrow[qt][r] = mnew;
                float rs = 0.f;
#pragma unroll
                for (int kt2 = 0; kt2 < 4; ++kt2) {
                    float p = __expf(sc[qt][kt2][r] - mnew);
                    sc[qt][kt2][r] = p;
                    rs += p;
                }
                for (int msk = 1; msk < 16; msk <<= 1)
                    rs += __shfl_xor(rs, msk);
                lrow[qt][r] = lrow[qt][r] * alpha[r] + rs;
            }
#pragma unroll
            for (int dt = 0; dt < 4; ++dt)
#pragma unroll
                for (int r = 0; r < 4; ++r)
                    accO[qt][dt][r] *= alpha[r];
            // P -> bf16 -> per-wave LDS (swizzled)
#pragma unroll
            for (int kt2 = 0; kt2 < 4; ++kt2)
#pragma unroll
                for (int r = 0; r < 4; ++r) {
                    int row = qt * 16 + ((lane >> 4) << 2) + r;
                    int colb = (kt2 * 16 + (lane & 15)) * 2;
                    int byteoff = row * 128 + (colb ^ ((row & 7) << 4));
                    *(u16*)((char*)Ps[w] + byteoff) = f2b(sc[qt][kt2][r]);
                }
        }
        asm volatile("s_waitcnt lgkmcnt(0)" ::: "memory");

        // O += P V  (16 MFMA)
#pragma unroll
        for (int kk = 0; kk < 2; ++kk) {
            bf16x8 pf[2], vf[4];
#pragma unroll
            for (int qt = 0; qt < 2; ++qt) {
                int row = qt * 16 + (lane & 15);
                int col = (kk * 64 + ((lane >> 4) << 4)) ^ ((row & 7) << 4);
                pf[qt] = *(const bf16x8*)((const char*)Ps[w] + row * 128 + col);
            }
#pragma unroll
            for (int dt = 0; dt < 4; ++dt) {
                int row = dt * 16 + (lane & 15);
                int col = (kk * 64 + ((lane >> 4) << 4)) ^ ((row & 7) << 4);
                vf[dt] = *(const bf16x8*)((const char*)Vs + row * 128 + col);
            }
#pragma unroll
            for (int qt = 0; qt < 2; ++qt)
#pragma unroll
                for (int dt = 0; dt < 4; ++dt)
                    accO[qt][dt] = __builtin_amdgcn_mfma_f32_16x16x32_bf16(
                        pf[qt], vf[dt], accO[qt][dt], 0, 0, 0);
        }
        __syncthreads();
    }

    // epilogue: 1/l, q_mask, write fp32 out[b][s][h*64+d]
#pragma unroll
    for (int qt = 0; qt < 2; ++qt)
#pragma unroll
        for (int r = 0; r < 4; ++r) {
            int row = q0 + qt * 16 + ((lane >> 4) << 2) + r;
            float qm = q_mask[b * SEQ + row];
            float denom = lrow[qt][r];
            float inv = (denom > 0.f) ? qm / denom : 0.f;
#pragma unroll
            for (int dt = 0; dt < 4; ++dt) {
                int d = dt * 16 + (lane & 15);
                out[((size_t)b * SEQ + row) * 768 + h * HD + d] = accO[qt][dt][r] * inv;
            }
        }
}

extern "C" void kernel_launch(void* const* d_in, const int* in_sizes, int n_in,
                              void* d_out, int out_size, void* d_ws, size_t ws_size,
                              hipStream_t stream) {
    const float* q      = (const float*)d_in[0];
    const float* k      = (const float*)d_in[1];
    const float* v      = (const float*)d_in[2];
    const float* vmask  = (const float*)d_in[3];
    const float* qmask  = (const float*)d_in[4];
    const float* Wq     = (const float*)d_in[5];
    const float* Wk     = (const float*)d_in[6];
    const float* Wv     = (const float*)d_in[7];
    float* out = (float*)d_out;

    u16* Xq  = (u16*)d_ws;
    u16* Xk  = Xq + (size_t)BS * DMODEL;
    u16* Xv  = Xk + (size_t)BS * DMODEL;
    u16* WTq = Xv + (size_t)BS * DMODEL;
    u16* WTk = WTq + (size_t)DMODEL * DMODEL;
    u16* WTv = WTk + (size_t)DMODEL * DMODEL;
    u16* qwp = WTv + (size_t)DMODEL * DMODEL;
    u16* kwp = qwp + (size_t)BATCH * HEADS * SEQ * HD;
    u16* vtp = kwp + (size_t)BATCH * HEADS * SEQ * HD;

    cvt_x<<<dim3(BS * DMODEL / 8 / 256, 1, 3), 256, 0, stream>>>(q, k, v, Xq, Xk, Xv);
    cvt_wt<<<dim3(DMODEL / 32, DMODEL / 32, 3), dim3(32, 8), 0, stream>>>(
        Wq, Wk, Wv, WTq, WTk, WTv);
    proj_gemm<<<dim3(BS / 128, DMODEL / 128, 3), 256, 0, stream>>>(
        Xq, Xk, Xv, WTq, WTk, WTv, qwp, kwp, vtp);
    attn<<<dim3(SEQ / 128, BATCH * HEADS), 256, 0, stream>>>(
        qwp, kwp, vtp, vmask, qmask, out);
}

// Round 2
// 111.629 us; speedup vs baseline: 1.3332x; 1.3332x over previous
//
#include <hip/hip_runtime.h>
#include <stdint.h>

#define HEADS 12
#define DMODEL 768
#define BATCH 2
#define SEQ 2048
#define BS (BATCH * SEQ)
#define HD 64

typedef float f32x4 __attribute__((ext_vector_type(4)));
typedef __bf16 bf16x8 __attribute__((ext_vector_type(8)));
typedef unsigned short u16;
typedef u16 u16x8 __attribute__((ext_vector_type(8)));
typedef u16 u16x4 __attribute__((ext_vector_type(4)));

__device__ __forceinline__ u16 f2b(float f) {
    return __builtin_bit_cast(u16, (__bf16)f);
}

__device__ __forceinline__ void gld_lds16(const void* g, void* l) {
    __builtin_amdgcn_global_load_lds(
        (__attribute__((address_space(1))) void*)(g),
        (__attribute__((address_space(3))) void*)(l), 16, 0, 0);
}
__device__ __forceinline__ void gld_lds4(const void* g, void* l) {
    __builtin_amdgcn_global_load_lds(
        (__attribute__((address_space(1))) void*)(g),
        (__attribute__((address_space(3))) void*)(l), 4, 0, 0);
}

// ---------------- prep: fp32 -> bf16 (vectorized) ----------------
__global__ __launch_bounds__(256) void cvt_x(
    const float* __restrict__ q, const float* __restrict__ k, const float* __restrict__ v,
    u16* __restrict__ xq, u16* __restrict__ xk, u16* __restrict__ xv) {
    int z = blockIdx.z;
    const float* s = (z == 0) ? q : (z == 1) ? k : v;
    u16* d = (z == 0) ? xq : (z == 1) ? xk : xv;
    size_t i = (size_t)blockIdx.x * blockDim.x + threadIdx.x;
    const float4* s4 = (const float4*)s;
    float4 a = s4[2 * i], b = s4[2 * i + 1];
    u16x8 o;
    o[0] = f2b(a.x); o[1] = f2b(a.y); o[2] = f2b(a.z); o[3] = f2b(a.w);
    o[4] = f2b(b.x); o[5] = f2b(b.y); o[6] = f2b(b.z); o[7] = f2b(b.w);
    *(u16x8*)(d + 8 * i) = o;
}

// ---------------- prep: W -> W^T bf16 ----------------
__global__ void cvt_wt(const float* __restrict__ wq, const float* __restrict__ wk,
                       const float* __restrict__ wv,
                       u16* __restrict__ tq, u16* __restrict__ tk, u16* __restrict__ tv) {
    int z = blockIdx.z;
    const float* w = (z == 0) ? wq : (z == 1) ? wk : wv;
    u16* t = (z == 0) ? tq : (z == 1) ? tk : tv;
    __shared__ float tile[32][33];
    int tx = threadIdx.x, ty = threadIdx.y;
    int kb = blockIdx.y * 32, nb = blockIdx.x * 32;
    for (int r = 0; r < 32; r += 8)
        tile[ty + r][tx] = w[(size_t)(kb + ty + r) * DMODEL + nb + tx];
    __syncthreads();
    for (int r = 0; r < 32; r += 8)
        t[(size_t)(nb + ty + r) * DMODEL + kb + tx] = f2b(tile[tx][ty + r]);
}

// ---------------- projection GEMM: C[m][n] = X[m][k] * W[k][n] ----------------
// z=0 -> qw [B,H,S,64] PRE-SCALED by 0.125*log2(e); z=1 -> kw [B,H,S,64];
// z=2 -> vt [B,H,64,S] (V stored transposed for attention)
__global__ __launch_bounds__(256, 2) void proj_gemm(
    const u16* __restrict__ xq, const u16* __restrict__ xk, const u16* __restrict__ xv,
    const u16* __restrict__ tq, const u16* __restrict__ tk, const u16* __restrict__ tv,
    u16* __restrict__ oq, u16* __restrict__ ok, u16* __restrict__ ov) {
    const int z = blockIdx.z;
    const u16* X  = (z == 0) ? xq : (z == 1) ? xk : xv;
    const u16* WT = (z == 0) ? tq : (z == 1) ? tk : tv;
    u16* Out      = (z == 0) ? oq : (z == 1) ? ok : ov;

    __shared__ u16 As[128 * 64];
    __shared__ u16 Bs[128 * 64];

    const int tid = threadIdx.x;
    const int lane = tid & 63, w = tid >> 6;
    const int wm = w >> 1, wn = w & 1;
    const int m0 = blockIdx.x * 128, n0 = blockIdx.y * 128;

    f32x4 acc[4][4] = {};

    for (int kt = 0; kt < DMODEL / 64; ++kt) {
#pragma unroll
        for (int p = 0; p < 4; ++p) {
            int o = (p * 4 + w) * 1024 + lane * 16;
            int row = o >> 7;
            int col = (o & 127) ^ ((row & 7) << 4);
            gld_lds16((const char*)X + (size_t)(m0 + row) * (DMODEL * 2) + kt * 128 + col,
                      (char*)As + (p * 4 + w) * 1024);
            gld_lds16((const char*)WT + (size_t)(n0 + row) * (DMODEL * 2) + kt * 128 + col,
                      (char*)Bs + (p * 4 + w) * 1024);
        }
        __syncthreads();
#pragma unroll
        for (int kk = 0; kk < 2; ++kk) {
            bf16x8 af[4], bfr[4];
#pragma unroll
            for (int mi = 0; mi < 4; ++mi) {
                int row = wm * 64 + mi * 16 + (lane & 15);
                int col = (kk * 64 + ((lane >> 4) << 4)) ^ ((row & 7) << 4);
                af[mi] = *(const bf16x8*)((const char*)As + row * 128 + col);
            }
#pragma unroll
            for (int ni = 0; ni < 4; ++ni) {
                int row = wn * 64 + ni * 16 + (lane & 15);
                int col = (kk * 64 + ((lane >> 4) << 4)) ^ ((row & 7) << 4);
                bfr[ni] = *(const bf16x8*)((const char*)Bs + row * 128 + col);
            }
#pragma unroll
            for (int mi = 0; mi < 4; ++mi)
#pragma unroll
                for (int ni = 0; ni < 4; ++ni)
                    acc[mi][ni] = __builtin_amdgcn_mfma_f32_16x16x32_bf16(
                        af[mi], bfr[ni], acc[mi][ni], 0, 0, 0);
        }
        __syncthreads();
    }

    const float mul = (z == 0) ? 0.125f * 1.44269504f : 1.0f;
#pragma unroll
    for (int mi = 0; mi < 4; ++mi) {
        int mb = m0 + wm * 64 + mi * 16 + ((lane >> 4) << 2);
#pragma unroll
        for (int ni = 0; ni < 4; ++ni) {
            int n = n0 + wn * 64 + ni * 16 + (lane & 15);
            int h = n >> 6, dd = n & 63;
#pragma unroll
            for (int r = 0; r < 4; ++r) {
                int m = mb + r;
                int b = m >> 11, s = m & 2047;
                u16 val = f2b(acc[mi][ni][r] * mul);
                size_t off = (z == 2)
                    ? ((size_t)(b * HEADS + h) * HD + dd) * SEQ + s
                    : ((size_t)(b * HEADS + h) * SEQ + s) * HD + dd;
                Out[off] = val;
            }
        }
    }
}

// ---------------- fused attention (swapped-QK^T, exp2 domain, 2-phase prefetch) ----
// qw: [B,H,S,64] bf16 pre-scaled by 0.125*log2e; kw: [B,H,S,64]; vt: [B,H,64,S]
__global__ __launch_bounds__(256, 2) void attn(
    const u16* __restrict__ qw, const u16* __restrict__ kw, const u16* __restrict__ vt,
    const float* __restrict__ v_mask, const float* __restrict__ q_mask,
    float* __restrict__ out) {
    __shared__ u16 Ks[2][64 * 64];            // [key][d] swizzled, double-buffered
    __shared__ u16 Vs[2][64 * 64];            // [d][key] swizzled (V^T)
    __shared__ __align__(16) float bias_s[2][64];  // raw v_mask values
    __shared__ u16 Ps[4][32 * 64];            // per-wave P^T as [q][key], swizzled

    const int tid = threadIdx.x;
    const int lane = tid & 63, w = tid >> 6;
    const int l15 = lane & 15, g = lane >> 4;
    const int bh = blockIdx.y;
    const int b = bh / HEADS, h = bh % HEADS;
    const int q0 = blockIdx.x * 128 + w * 32;

    const u16* qb = qw + (size_t)bh * SEQ * HD;
    const u16* kb = kw + (size_t)bh * SEQ * HD;
    const u16* vb = vt + (size_t)bh * HD * SEQ;
    const float* vmaskb = v_mask + (size_t)b * SEQ;

    // hoist Q fragments (B-operand layout: col=lane&15, k=8*(lane>>4)+j)
    bf16x8 qf[2][2];
#pragma unroll
    for (int qt = 0; qt < 2; ++qt)
#pragma unroll
        for (int kk = 0; kk < 2; ++kk) {
            int row = q0 + qt * 16 + l15;
            int cb = kk * 64 + (g << 4);
            qf[qt][kk] = *(const bf16x8*)((const char*)(qb + (size_t)row * HD) + cb);
        }

    f32x4 accO[2][4] = {};          // O^T: accO[qt][dt][r] = O[q][d=dt*16+g*4+r]
    float mrow[2] = {-1e30f, -1e30f};
    float lpart[2] = {0.f, 0.f};    // per-lane partial row-sums (reduced at epilogue)

    auto stage = [&](int t, int p) {
        const int kv0 = t * 64;
#pragma unroll
        for (int i = 0; i < 2; ++i) {
            int o = (i * 4 + w) * 1024 + lane * 16;
            int row = o >> 7;
            int col = (o & 127) ^ ((row & 7) << 4);
            gld_lds16((const char*)kb + (size_t)(kv0 + row) * 128 + col,
                      (char*)Ks[p] + (i * 4 + w) * 1024);
            gld_lds16((const char*)vb + (size_t)row * (SEQ * 2) + (size_t)kv0 * 2 + col,
                      (char*)Vs[p] + (i * 4 + w) * 1024);
        }
        // all 4 waves load the same 256B (keeps per-wave vmcnt uniform; benign dup)
        gld_lds4(vmaskb + kv0 + lane, (char*)bias_s[p]);
    };

    stage(0, 0);
    __syncthreads();

    for (int t = 0; t < SEQ / 64; ++t) {
        const int cur = t & 1;
        if (t + 1 < SEQ / 64) stage(t + 1, cur ^ 1);

        // ---- S^T = K Q^T  (16 MFMA): sc[qt][kt][r] = S[key=kt*16+g*4+r][q=qt*16+l15]
        f32x4 sc[2][4] = {};
#pragma unroll
        for (int kk = 0; kk < 2; ++kk) {
            bf16x8 kf[4];
#pragma unroll
            for (int kt = 0; kt < 4; ++kt) {
                int row = kt * 16 + l15;
                int colB = (kk * 64 + (g << 4)) ^ ((row & 7) << 4);
                kf[kt] = *(const bf16x8*)((const char*)Ks[cur] + row * 128 + colB);
            }
#pragma unroll
            for (int qt = 0; qt < 2; ++qt)
#pragma unroll
                for (int kt = 0; kt < 4; ++kt)
                    sc[qt][kt] = __builtin_amdgcn_mfma_f32_16x16x32_bf16(
                        kf[kt], qf[qt][kk], sc[qt][kt], 0, 0, 0);
        }

        // ---- mask bias (log2 domain), shared across qt
        float bb[4][4];
#pragma unroll
        for (int kt = 0; kt < 4; ++kt) {
            f32x4 vv = *(const f32x4*)(&bias_s[cur][kt * 16 + g * 4]);
#pragma unroll
            for (int r = 0; r < 4; ++r)
                bb[kt][r] = (1.0f - vv[r]) * -1.442695e10f;
        }

        // ---- online softmax: 16 in-lane values per q, 2 shuffles for the max
#pragma unroll
        for (int qt = 0; qt < 2; ++qt) {
            float s[4][4];
            float tmax = -1e30f;
#pragma unroll
            for (int kt = 0; kt < 4; ++kt)
#pragma unroll
                for (int r = 0; r < 4; ++r) {
                    float val = sc[qt][kt][r] + bb[kt][r];
                    s[kt][r] = val;
                    tmax = fmaxf(tmax, val);
                }
            tmax = fmaxf(tmax, __shfl_xor(tmax, 16));
            tmax = fmaxf(tmax, __shfl_xor(tmax, 32));
            float m = mrow[qt];
            if (!__all(tmax - m <= 11.0f)) {   // defer-max: P bounded by 2^11
                float mnew = fmaxf(m, tmax);
                float al = __builtin_amdgcn_exp2f(m - mnew);
                mrow[qt] = mnew;
                lpart[qt] *= al;
#pragma unroll
                for (int dt = 0; dt < 4; ++dt) accO[qt][dt] *= al;
                m = mnew;
            }
            float lsum = 0.f;
#pragma unroll
            for (int kt = 0; kt < 4; ++kt) {
                u16x4 pv;
#pragma unroll
                for (int r = 0; r < 4; ++r) {
                    float p = __builtin_amdgcn_exp2f(s[kt][r] - m);
                    lsum += p;
                    pv[r] = f2b(p);
                }
                int row = qt * 16 + l15;
                int colB = (kt * 32 + g * 8) ^ ((row & 7) << 4);
                *(u16x4*)((char*)Ps[w] + row * 128 + colB) = pv;
            }
            lpart[qt] += lsum;
        }

        // ---- O^T += V^T P^T  (16 MFMA)
#pragma unroll
        for (int kk = 0; kk < 2; ++kk) {
            bf16x8 pf[2], vf[4];
#pragma unroll
            for (int qt = 0; qt < 2; ++qt) {
                int row = qt * 16 + l15;
                int colB = (kk * 64 + (g << 4)) ^ ((row & 7) << 4);
                pf[qt] = *(const bf16x8*)((const char*)Ps[w] + row * 128 + colB);
            }
#pragma unroll
            for (int dt = 0; dt < 4; ++dt) {
                int row = dt * 16 + l15;
                int colB = (kk * 64 + (g << 4)) ^ ((row & 7) << 4);
                vf[dt] = *(const bf16x8*)((const char*)Vs[cur] + row * 128 + colB);
            }
#pragma unroll
            for (int qt = 0; qt < 2; ++qt)
#pragma unroll
                for (int dt = 0; dt < 4; ++dt)
                    accO[qt][dt] = __builtin_amdgcn_mfma_f32_16x16x32_bf16(
                        vf[dt], pf[qt], accO[qt][dt], 0, 0, 0);
        }
        __syncthreads();
    }

    // ---- epilogue: reduce l across lane groups, apply q_mask, float4 stores
#pragma unroll
    for (int qt = 0; qt < 2; ++qt) {
        float lq = lpart[qt];
        lq += __shfl_xor(lq, 16);
        lq += __shfl_xor(lq, 32);
        int qrow = q0 + qt * 16 + l15;
        float qm = q_mask[(size_t)b * SEQ + qrow];
        float inv = (lq > 0.f) ? qm / lq : 0.f;
#pragma unroll
        for (int dt = 0; dt < 4; ++dt) {
            f32x4 o = accO[qt][dt] * inv;
            *(f32x4*)(&out[((size_t)b * SEQ + qrow) * 768 + h * HD + dt * 16 + g * 4]) = o;
        }
    }
}

extern "C" void kernel_launch(void* const* d_in, const int* in_sizes, int n_in,
                              void* d_out, int out_size, void* d_ws, size_t ws_size,
                              hipStream_t stream) {
    const float* q      = (const float*)d_in[0];
    const float* k      = (const float*)d_in[1];
    const float* v      = (const float*)d_in[2];
    const float* vmask  = (const float*)d_in[3];
    const float* qmask  = (const float*)d_in[4];
    const float* Wq     = (const float*)d_in[5];
    const float* Wk     = (const float*)d_in[6];
    const float* Wv     = (const float*)d_in[7];
    float* out = (float*)d_out;

    u16* Xq  = (u16*)d_ws;
    u16* Xk  = Xq + (size_t)BS * DMODEL;
    u16* Xv  = Xk + (size_t)BS * DMODEL;
    u16* WTq = Xv + (size_t)BS * DMODEL;
    u16* WTk = WTq + (size_t)DMODEL * DMODEL;
    u16* WTv = WTk + (size_t)DMODEL * DMODEL;
    u16* qwp = WTv + (size_t)DMODEL * DMODEL;
    u16* kwp = qwp + (size_t)BATCH * HEADS * SEQ * HD;
    u16* vtp = kwp + (size_t)BATCH * HEADS * SEQ * HD;

    cvt_x<<<dim3(BS * DMODEL / 8 / 256, 1, 3), 256, 0, stream>>>(q, k, v, Xq, Xk, Xv);
    cvt_wt<<<dim3(DMODEL / 32, DMODEL / 32, 3), dim3(32, 8), 0, stream>>>(
        Wq, Wk, Wv, WTq, WTk, WTv);
    proj_gemm<<<dim3(BS / 128, DMODEL / 128, 3), 256, 0, stream>>>(
        Xq, Xk, Xv, WTq, WTk, WTv, qwp, kwp, vtp);
    attn<<<dim3(SEQ / 128, BATCH * HEADS), 256, 0, stream>>>(
        qwp, kwp, vtp, vmask, qmask, out);
}

// Round 5
// 99.930 us; speedup vs baseline: 1.4893x; 1.1171x over previous
//
#include <hip/hip_runtime.h>
#include <stdint.h>

#define HEADS 12
#define DMODEL 768
#define BATCH 2
#define SEQ 2048
#define BS (BATCH * SEQ)
#define HD 64

typedef float f32x4 __attribute__((ext_vector_type(4)));
typedef __bf16 bf16x8 __attribute__((ext_vector_type(8)));
typedef unsigned short u16;
typedef u16 u16x8 __attribute__((ext_vector_type(8)));
typedef u16 u16x4 __attribute__((ext_vector_type(4)));

__device__ __forceinline__ u16 f2b(float f) {
    return __builtin_bit_cast(u16, (__bf16)f);
}

__device__ __forceinline__ void gld_lds16(const void* g, void* l) {
    __builtin_amdgcn_global_load_lds(
        (__attribute__((address_space(1))) void*)(g),
        (__attribute__((address_space(3))) void*)(l), 16, 0, 0);
}
__device__ __forceinline__ void gld_lds4(const void* g, void* l) {
    __builtin_amdgcn_global_load_lds(
        (__attribute__((address_space(1))) void*)(g),
        (__attribute__((address_space(3))) void*)(l), 4, 0, 0);
}

// ---------------- prep: fp32 -> bf16 (vectorized) ----------------
__global__ __launch_bounds__(256) void cvt_x(
    const float* __restrict__ q, const float* __restrict__ k, const float* __restrict__ v,
    u16* __restrict__ xq, u16* __restrict__ xk, u16* __restrict__ xv) {
    int z = blockIdx.z;
    const float* s = (z == 0) ? q : (z == 1) ? k : v;
    u16* d = (z == 0) ? xq : (z == 1) ? xk : xv;
    size_t i = (size_t)blockIdx.x * blockDim.x + threadIdx.x;
    const float4* s4 = (const float4*)s;
    float4 a = s4[2 * i], b = s4[2 * i + 1];
    u16x8 o;
    o[0] = f2b(a.x); o[1] = f2b(a.y); o[2] = f2b(a.z); o[3] = f2b(a.w);
    o[4] = f2b(b.x); o[5] = f2b(b.y); o[6] = f2b(b.z); o[7] = f2b(b.w);
    *(u16x8*)(d + 8 * i) = o;
}

// ---------------- prep: W -> W^T bf16 ----------------
__global__ void cvt_wt(const float* __restrict__ wq, const float* __restrict__ wk,
                       const float* __restrict__ wv,
                       u16* __restrict__ tq, u16* __restrict__ tk, u16* __restrict__ tv) {
    int z = blockIdx.z;
    const float* w = (z == 0) ? wq : (z == 1) ? wk : wv;
    u16* t = (z == 0) ? tq : (z == 1) ? tk : tv;
    __shared__ float tile[32][33];
    int tx = threadIdx.x, ty = threadIdx.y;
    int kb = blockIdx.y * 32, nb = blockIdx.x * 32;
    for (int r = 0; r < 32; r += 8)
        tile[ty + r][tx] = w[(size_t)(kb + ty + r) * DMODEL + nb + tx];
    __syncthreads();
    for (int r = 0; r < 32; r += 8)
        t[(size_t)(nb + ty + r) * DMODEL + kb + tx] = f2b(tile[tx][ty + r]);
}

// ---------------- projection GEMM: C[m][n] = X[m][k] * W[k][n] ----------------
// z=0 -> qw [B,H,S,64] PRE-SCALED by 0.125*log2(e); z=1 -> kw [B,H,S,64];
// z=2 -> vt [B,H,64,S] (V stored transposed for attention)
__global__ __launch_bounds__(256, 2) void proj_gemm(
    const u16* __restrict__ xq, const u16* __restrict__ xk, const u16* __restrict__ xv,
    const u16* __restrict__ tq, const u16* __restrict__ tk, const u16* __restrict__ tv,
    u16* __restrict__ oq, u16* __restrict__ ok, u16* __restrict__ ov) {
    const int z = blockIdx.z;
    const u16* X  = (z == 0) ? xq : (z == 1) ? xk : xv;
    const u16* WT = (z == 0) ? tq : (z == 1) ? tk : tv;
    u16* Out      = (z == 0) ? oq : (z == 1) ? ok : ov;

    __shared__ u16 As[128 * 64];
    __shared__ u16 Bs[128 * 64];

    const int tid = threadIdx.x;
    const int lane = tid & 63, w = tid >> 6;
    const int wm = w >> 1, wn = w & 1;
    const int m0 = blockIdx.x * 128, n0 = blockIdx.y * 128;

    f32x4 acc[4][4] = {};

    for (int kt = 0; kt < DMODEL / 64; ++kt) {
#pragma unroll
        for (int p = 0; p < 4; ++p) {
            int o = (p * 4 + w) * 1024 + lane * 16;
            int row = o >> 7;
            int col = (o & 127) ^ ((row & 7) << 4);
            gld_lds16((const char*)X + (size_t)(m0 + row) * (DMODEL * 2) + kt * 128 + col,
                      (char*)As + (p * 4 + w) * 1024);
            gld_lds16((const char*)WT + (size_t)(n0 + row) * (DMODEL * 2) + kt * 128 + col,
                      (char*)Bs + (p * 4 + w) * 1024);
        }
        __syncthreads();
#pragma unroll
        for (int kk = 0; kk < 2; ++kk) {
            bf16x8 af[4], bfr[4];
#pragma unroll
            for (int mi = 0; mi < 4; ++mi) {
                int row = wm * 64 + mi * 16 + (lane & 15);
                int col = (kk * 64 + ((lane >> 4) << 4)) ^ ((row & 7) << 4);
                af[mi] = *(const bf16x8*)((const char*)As + row * 128 + col);
            }
#pragma unroll
            for (int ni = 0; ni < 4; ++ni) {
                int row = wn * 64 + ni * 16 + (lane & 15);
                int col = (kk * 64 + ((lane >> 4) << 4)) ^ ((row & 7) << 4);
                bfr[ni] = *(const bf16x8*)((const char*)Bs + row * 128 + col);
            }
#pragma unroll
            for (int mi = 0; mi < 4; ++mi)
#pragma unroll
                for (int ni = 0; ni < 4; ++ni)
                    acc[mi][ni] = __builtin_amdgcn_mfma_f32_16x16x32_bf16(
                        af[mi], bfr[ni], acc[mi][ni], 0, 0, 0);
        }
        __syncthreads();
    }

    const float mul = (z == 0) ? 0.125f * 1.44269504f : 1.0f;
#pragma unroll
    for (int mi = 0; mi < 4; ++mi) {
        int mb = m0 + wm * 64 + mi * 16 + ((lane >> 4) << 2);
#pragma unroll
        for (int ni = 0; ni < 4; ++ni) {
            int n = n0 + wn * 64 + ni * 16 + (lane & 15);
            int h = n >> 6, dd = n & 63;
#pragma unroll
            for (int r = 0; r < 4; ++r) {
                int m = mb + r;
                int b = m >> 11, s = m & 2047;
                u16 val = f2b(acc[mi][ni][r] * mul);
                size_t off = (z == 2)
                    ? ((size_t)(b * HEADS + h) * HD + dd) * SEQ + s
                    : ((size_t)(b * HEADS + h) * SEQ + s) * HD + dd;
                Out[off] = val;
            }
        }
    }
}

// ---------------- fused attention ----------------
// 16 q-rows per wave, 64 per block (grid 32x24 = 768 blocks = 3/CU);
// swapped QK^T, exp2 domain, 2-phase prefetch; round-2-proven XOR-swizzled Ps.
// qw: [B,H,S,64] bf16 pre-scaled by 0.125*log2e; kw: [B,H,S,64]; vt: [B,H,64,S]
__global__ __launch_bounds__(256, 3) void attn(
    const u16* __restrict__ qw, const u16* __restrict__ kw, const u16* __restrict__ vt,
    const float* __restrict__ v_mask, const float* __restrict__ q_mask,
    float* __restrict__ out) {
    __shared__ u16 Ks[2][64 * 64];            // [key][d] swizzled, double-buffered
    __shared__ u16 Vs[2][64 * 64];            // [d][key] swizzled (V^T)
    __shared__ __align__(16) float bias_s[2][64];
    __shared__ u16 Ps[4][16 * 64];            // per-wave P^T [q][key], XOR-swizzled

    const int tid = threadIdx.x;
    const int lane = tid & 63, w = tid >> 6;
    const int l15 = lane & 15, g = lane >> 4;
    const int bh = blockIdx.y;
    const int b = bh / HEADS, h = bh % HEADS;
    const int q0 = blockIdx.x * 64 + w * 16;

    const u16* qb = qw + (size_t)bh * SEQ * HD;
    const u16* kb = kw + (size_t)bh * SEQ * HD;
    const u16* vb = vt + (size_t)bh * HD * SEQ;
    const float* vmaskb = v_mask + (size_t)b * SEQ;

    // hoist Q fragments (B-operand layout: col=lane&15, k=8*(lane>>4)+j + 32*kk)
    bf16x8 qf[2];
#pragma unroll
    for (int kk = 0; kk < 2; ++kk) {
        int row = q0 + l15;
        qf[kk] = *(const bf16x8*)((const char*)(qb + (size_t)row * HD) + kk * 64 + (g << 4));
    }

    f32x4 accO[4] = {};           // O^T: accO[dt][r] = O[q=l15][d=dt*16+g*4+r]
    float mrow = -1e30f;
    float lpart = 0.f;

    auto stage = [&](int t, int p) {
        const int kv0 = t * 64;
#pragma unroll
        for (int i = 0; i < 2; ++i) {
            int o = (i * 4 + w) * 1024 + lane * 16;
            int row = o >> 7;
            int col = (o & 127) ^ ((row & 7) << 4);
            gld_lds16((const char*)kb + (size_t)(kv0 + row) * 128 + col,
                      (char*)Ks[p] + (i * 4 + w) * 1024);
            gld_lds16((const char*)vb + (size_t)row * (SEQ * 2) + (size_t)kv0 * 2 + col,
                      (char*)Vs[p] + (i * 4 + w) * 1024);
        }
        gld_lds4(vmaskb + kv0 + lane, (char*)bias_s[p]);
    };

    stage(0, 0);
    __syncthreads();

    for (int t = 0; t < SEQ / 64; ++t) {
        const int cur = t & 1;
        if (t + 1 < SEQ / 64) stage(t + 1, cur ^ 1);

        // ---- S^T = K Q^T (8 MFMA): sc[kt][r] = S[key=kt*16+g*4+r][q=l15]
        f32x4 sc[4] = {};
#pragma unroll
        for (int kk = 0; kk < 2; ++kk) {
            bf16x8 kf[4];
#pragma unroll
            for (int kt = 0; kt < 4; ++kt) {
                int row = kt * 16 + l15;
                int colB = (kk * 64 + (g << 4)) ^ ((row & 7) << 4);
                kf[kt] = *(const bf16x8*)((const char*)Ks[cur] + row * 128 + colB);
            }
#pragma unroll
            for (int kt = 0; kt < 4; ++kt)
                sc[kt] = __builtin_amdgcn_mfma_f32_16x16x32_bf16(
                    kf[kt], qf[kk], sc[kt], 0, 0, 0);
        }

        // ---- mask bias (log2 domain)
        float bb[4][4];
#pragma unroll
        for (int kt = 0; kt < 4; ++kt) {
            f32x4 vv = *(const f32x4*)(&bias_s[cur][kt * 16 + g * 4]);
#pragma unroll
            for (int r = 0; r < 4; ++r)
                bb[kt][r] = (1.0f - vv[r]) * -1.442695e10f;
        }

        // ---- online softmax: 16 in-lane values per q, 2 shuffles for the max
        float s[4][4];
        float tmax = -1e30f;
#pragma unroll
        for (int kt = 0; kt < 4; ++kt)
#pragma unroll
            for (int r = 0; r < 4; ++r) {
                float val = sc[kt][r] + bb[kt][r];
                s[kt][r] = val;
                tmax = fmaxf(tmax, val);
            }
        tmax = fmaxf(tmax, __shfl_xor(tmax, 16));
        tmax = fmaxf(tmax, __shfl_xor(tmax, 32));
        float m = mrow;
        if (!__all(tmax - m <= 8.0f)) {    // defer-max: P bounded by 2^8
            float mnew = fmaxf(m, tmax);
            float al = __builtin_amdgcn_exp2f(m - mnew);
            mrow = mnew;
            lpart *= al;
#pragma unroll
            for (int dt = 0; dt < 4; ++dt) accO[dt] *= al;
            m = mnew;
        }
        float lsum = 0.f;
#pragma unroll
        for (int kt = 0; kt < 4; ++kt) {
            u16x4 pv;
#pragma unroll
            for (int r = 0; r < 4; ++r) {
                float p = __builtin_amdgcn_exp2f(s[kt][r] - m);
                lsum += p;
                pv[r] = f2b(p);
            }
            // round-2-proven layout: physical byte = logical ^ ((row&7)<<4)
            int colB = (kt * 32 + g * 8) ^ ((l15 & 7) << 4);
            *(u16x4*)((char*)Ps[w] + l15 * 128 + colB) = pv;
        }
        lpart += lsum;

        // COMPILER FENCE: the P round-trip is a cross-lane exchange through LDS;
        // force all P stores to be emitted before any P read.
        asm volatile("s_waitcnt lgkmcnt(0)" ::: "memory");

        // ---- O^T += V^T P^T (8 MFMA); P read as single 16B-aligned bf16x8
#pragma unroll
        for (int kk = 0; kk < 2; ++kk) {
            int colP = (kk * 64 + (g << 4)) ^ ((l15 & 7) << 4);
            bf16x8 pf = *(const bf16x8*)((const char*)Ps[w] + l15 * 128 + colP);
            bf16x8 vf[4];
#pragma unroll
            for (int dt = 0; dt < 4; ++dt) {
                int row = dt * 16 + l15;
                int colB = (kk * 64 + (g << 4)) ^ ((row & 7) << 4);
                vf[dt] = *(const bf16x8*)((const char*)Vs[cur] + row * 128 + colB);
            }
#pragma unroll
            for (int dt = 0; dt < 4; ++dt)
                accO[dt] = __builtin_amdgcn_mfma_f32_16x16x32_bf16(
                    vf[dt], pf, accO[dt], 0, 0, 0);
        }
        __syncthreads();
    }

    // ---- epilogue: reduce l across lane groups, apply q_mask, float4 stores
    float lq = lpart;
    lq += __shfl_xor(lq, 16);
    lq += __shfl_xor(lq, 32);
    int qrow = q0 + l15;
    float qm = q_mask[(size_t)b * SEQ + qrow];
    float inv = (lq > 0.f) ? qm / lq : 0.f;
#pragma unroll
    for (int dt = 0; dt < 4; ++dt) {
        f32x4 o = accO[dt] * inv;
        *(f32x4*)(&out[((size_t)b * SEQ + qrow) * 768 + h * HD + dt * 16 + g * 4]) = o;
    }
}

extern "C" void kernel_launch(void* const* d_in, const int* in_sizes, int n_in,
                              void* d_out, int out_size, void* d_ws, size_t ws_size,
                              hipStream_t stream) {
    const float* q      = (const float*)d_in[0];
    const float* k      = (const float*)d_in[1];
    const float* v      = (const float*)d_in[2];
    const float* vmask  = (const float*)d_in[3];
    const float* qmask  = (const float*)d_in[4];
    const float* Wq     = (const float*)d_in[5];
    const float* Wk     = (const float*)d_in[6];
    const float* Wv     = (const float*)d_in[7];
    float* out = (float*)d_out;

    u16* Xq  = (u16*)d_ws;
    u16* Xk  = Xq + (size_t)BS * DMODEL;
    u16* Xv  = Xk + (size_t)BS * DMODEL;
    u16* WTq = Xv + (size_t)BS * DMODEL;
    u16* WTk = WTq + (size_t)DMODEL * DMODEL;
    u16* WTv = WTk + (size_t)DMODEL * DMODEL;
    u16* qwp = WTv + (size_t)DMODEL * DMODEL;
    u16* kwp = qwp + (size_t)BATCH * HEADS * SEQ * HD;
    u16* vtp = kwp + (size_t)BATCH * HEADS * SEQ * HD;

    cvt_x<<<dim3(BS * DMODEL / 8 / 256, 1, 3), 256, 0, stream>>>(q, k, v, Xq, Xk, Xv);
    cvt_wt<<<dim3(DMODEL / 32, DMODEL / 32, 3), dim3(32, 8), 0, stream>>>(
        Wq, Wk, Wv, WTq, WTk, WTv);
    proj_gemm<<<dim3(BS / 128, DMODEL / 128, 3), 256, 0, stream>>>(
        Xq, Xk, Xv, WTq, WTk, WTv, qwp, kwp, vtp);
    attn<<<dim3(SEQ / 64, BATCH * HEADS), 256, 0, stream>>>(
        qwp, kwp, vtp, vmask, qmask, out);
}